// Round 1
// baseline (915.069 us; speedup 1.0000x reference)
//
#include <hip/hip_runtime.h>
#include <hip/hip_bf16.h>
#include <math.h>

// NetVLAD fp32 baseline (R1).
// B=32, D=512, N=3136 (56x56), K=64.
// Pipeline:
//   1. transpose_w:      wt[d][k] = conv_w[k][d]
//   2. logits_softmax:   alpha[b][k][n] = softmax_k(W x + b)   (2 pixels/thread, W staged in LDS)
//   3. asum_kernel:      asum[b][k] = sum_n alpha
//   4. vlad_gemm:        vlad[b][d][k] = sum_n alpha*x - centers*asum   (64x64 tile/block)
//   5. colnorm_kernel:   cninv[b][k] = 1/(||vlad[b,:,k]|| * 8)   (global norm of K unit cols == 8)
//   6. scale_out:        out = vlad * cninv
// fp32 throughout -> absmax ~1e-5 vs threshold 4.5e-4.

#define BB 32
#define DD 512
#define KK 64
#define NPIX 3136

// ---------------------------------------------------------------- kernel 1
__global__ __launch_bounds__(256) void transpose_w(
    const float* __restrict__ w, float* __restrict__ wt)
{
    int i = blockIdx.x * 256 + threadIdx.x;   // < 32768
    int d = i >> 6, k = i & 63;
    wt[i] = w[k * DD + d];
}

// ---------------------------------------------------------------- kernel 2
// grid (7, 32), block 256. Each thread: 2 pixels, 64 logit accumulators each.
__global__ __launch_bounds__(256) void logits_softmax(
    const float* __restrict__ x,      // [B,D,N]
    const float* __restrict__ wt,     // [D,K]
    const float* __restrict__ bias,   // [K]
    float* __restrict__ alpha)        // [B,K,N]
{
    const int b  = blockIdx.y;
    const int n0 = blockIdx.x * 512 + threadIdx.x;
    const int n1 = n0 + 256;
    const bool v0 = n0 < NPIX, v1 = n1 < NPIX;
    const int m0 = v0 ? n0 : 0, m1 = v1 ? n1 : 0;

    __shared__ __align__(16) float wls[64][64];   // one 64-d chunk of wt

    float acc0[KK], acc1[KK];
    #pragma unroll
    for (int k = 0; k < KK; k++) { float bk = bias[k]; acc0[k] = bk; acc1[k] = bk; }

    const float* xb = x + (size_t)b * DD * NPIX;

    for (int dc = 0; dc < DD / 64; dc++) {
        __syncthreads();
        #pragma unroll
        for (int j = 0; j < 16; j++) {
            int i = j * 256 + threadIdx.x;       // 0..4095
            wls[i >> 6][i & 63] = wt[(dc * 64 + (i >> 6)) * KK + (i & 63)];
        }
        __syncthreads();
        #pragma unroll 4
        for (int dl = 0; dl < 64; dl++) {
            const size_t roff = (size_t)(dc * 64 + dl) * NPIX;
            const float xv0 = xb[roff + m0];
            const float xv1 = xb[roff + m1];
            #pragma unroll
            for (int k4 = 0; k4 < 16; k4++) {
                // uniform address across the wave -> LDS broadcast, conflict-free
                float4 wv = *(const float4*)&wls[dl][k4 * 4];
                acc0[k4*4+0] = fmaf(wv.x, xv0, acc0[k4*4+0]);
                acc0[k4*4+1] = fmaf(wv.y, xv0, acc0[k4*4+1]);
                acc0[k4*4+2] = fmaf(wv.z, xv0, acc0[k4*4+2]);
                acc0[k4*4+3] = fmaf(wv.w, xv0, acc0[k4*4+3]);
                acc1[k4*4+0] = fmaf(wv.x, xv1, acc1[k4*4+0]);
                acc1[k4*4+1] = fmaf(wv.y, xv1, acc1[k4*4+1]);
                acc1[k4*4+2] = fmaf(wv.z, xv1, acc1[k4*4+2]);
                acc1[k4*4+3] = fmaf(wv.w, xv1, acc1[k4*4+3]);
            }
        }
    }

    // softmax over K, per pixel, entirely in registers
    float mx0 = -1e30f, mx1 = -1e30f;
    #pragma unroll
    for (int k = 0; k < KK; k++) { mx0 = fmaxf(mx0, acc0[k]); mx1 = fmaxf(mx1, acc1[k]); }
    float s0 = 0.f, s1 = 0.f;
    #pragma unroll
    for (int k = 0; k < KK; k++) {
        float e0 = __expf(acc0[k] - mx0); acc0[k] = e0; s0 += e0;
        float e1 = __expf(acc1[k] - mx1); acc1[k] = e1; s1 += e1;
    }
    const float r0 = 1.0f / s0, r1 = 1.0f / s1;

    float* ab = alpha + (size_t)b * KK * NPIX;
    #pragma unroll
    for (int k = 0; k < KK; k++) {
        if (v0) ab[(size_t)k * NPIX + n0] = acc0[k] * r0;
        if (v1) ab[(size_t)k * NPIX + n1] = acc1[k] * r1;
    }
}

// ---------------------------------------------------------------- kernel 3
// grid 2048 (= B*K), block 64 (one wave): row sum of alpha.
__global__ __launch_bounds__(64) void asum_kernel(
    const float* __restrict__ alpha, float* __restrict__ asum)
{
    const int row = blockIdx.x;                  // b*K + k
    const float* p = alpha + (size_t)row * NPIX;
    float s = 0.f;
    for (int n = threadIdx.x; n < NPIX; n += 64) s += p[n];
    #pragma unroll
    for (int off = 32; off; off >>= 1) s += __shfl_down(s, off);
    if (threadIdx.x == 0) asum[row] = s;
}

// ---------------------------------------------------------------- kernel 4
// grid (8, 32), block 256. Output tile 64(d) x 64(k) per block.
// Thread t: tk = t&15, td = t>>4; covers k = kk*16+tk (kk<4), d = dtile*64 + dd*16 + td (dd<4).
// LDS row stride 68 -> worst read pattern is a free 2-way bank conflict.
__global__ __launch_bounds__(256) void vlad_gemm(
    const float* __restrict__ x,        // [B,D,N]
    const float* __restrict__ alpha,    // [B,K,N]
    const float* __restrict__ centers,  // [D,K]
    const float* __restrict__ asum,     // [B,K]
    float* __restrict__ vlad)           // [B,D,K]
{
    const int dtile = blockIdx.x;       // 0..7
    const int b     = blockIdx.y;
    const int t     = threadIdx.x;
    const int tk    = t & 15;
    const int td    = t >> 4;

    __shared__ __align__(16) float xs[64][68];
    __shared__ __align__(16) float as[64][68];

    float acc[4][4] = {{0.f}};

    const float* xb = x + ((size_t)b * DD + dtile * 64) * NPIX;
    const float* ab = alpha + (size_t)b * KK * NPIX;

    for (int nc = 0; nc < NPIX; nc += 64) {       // 49 chunks
        #pragma unroll
        for (int j = 0; j < 16; j++) {
            int i = j * 256 + t;                  // 0..4095
            int row = i >> 6, col = i & 63;
            xs[row][col] = xb[(size_t)row * NPIX + nc + col];
            as[row][col] = ab[(size_t)row * NPIX + nc + col];
        }
        __syncthreads();
        #pragma unroll
        for (int n4 = 0; n4 < 16; n4++) {
            float4 av[4], xv[4];
            #pragma unroll
            for (int kk = 0; kk < 4; kk++) av[kk] = *(const float4*)&as[kk * 16 + tk][n4 * 4];
            #pragma unroll
            for (int dd = 0; dd < 4; dd++) xv[dd] = *(const float4*)&xs[dd * 16 + td][n4 * 4];
            #pragma unroll
            for (int dd = 0; dd < 4; dd++)
                #pragma unroll
                for (int kk = 0; kk < 4; kk++) {
                    acc[dd][kk] = fmaf(xv[dd].x, av[kk].x, acc[dd][kk]);
                    acc[dd][kk] = fmaf(xv[dd].y, av[kk].y, acc[dd][kk]);
                    acc[dd][kk] = fmaf(xv[dd].z, av[kk].z, acc[dd][kk]);
                    acc[dd][kk] = fmaf(xv[dd].w, av[kk].w, acc[dd][kk]);
                }
        }
        __syncthreads();
    }

    #pragma unroll
    for (int dd = 0; dd < 4; dd++) {
        const int d = dtile * 64 + dd * 16 + td;
        #pragma unroll
        for (int kk = 0; kk < 4; kk++) {
            const int k = kk * 16 + tk;
            float v = acc[dd][kk] - centers[d * KK + k] * asum[b * KK + k];
            vlad[((size_t)b * DD + d) * KK + k] = v;
        }
    }
}

// ---------------------------------------------------------------- kernel 5
// grid 32 (b), block 256: column sum-of-squares over d, then 1/(norm*8).
__global__ __launch_bounds__(256) void colnorm_kernel(
    const float* __restrict__ vlad, float* __restrict__ cninv)
{
    const int b  = blockIdx.x;
    const int k  = threadIdx.x & 63;
    const int dq = threadIdx.x >> 6;
    const float* vb = vlad + (size_t)b * DD * KK;
    float s = 0.f;
    for (int d = dq; d < DD; d += 4) { float v = vb[(size_t)d * KK + k]; s = fmaf(v, v, s); }
    __shared__ float red[4][64];
    red[dq][k] = s;
    __syncthreads();
    if (threadIdx.x < 64) {
        float tot = red[0][threadIdx.x] + red[1][threadIdx.x]
                  + red[2][threadIdx.x] + red[3][threadIdx.x];
        // after intra-norm each of the K columns is unit -> global norm == sqrt(K) == 8
        cninv[b * KK + threadIdx.x] = 1.0f / (sqrtf(tot) * 8.0f);
    }
}

// ---------------------------------------------------------------- kernel 6
// grid 1024, block 256, float4: out = vlad * cninv
__global__ __launch_bounds__(256) void scale_out(
    const float* __restrict__ vlad, const float* __restrict__ cninv,
    float* __restrict__ out)
{
    const int i4 = (blockIdx.x * 256 + threadIdx.x) * 4;   // < 1048576
    float4 v = *(const float4*)&vlad[i4];
    const int b = i4 >> 15;          // / (D*K)
    const int k = i4 & 63;           // multiple of 4
    float4 c = *(const float4*)&cninv[b * KK + k];
    float4 o; o.x = v.x * c.x; o.y = v.y * c.y; o.z = v.z * c.z; o.w = v.w * c.w;
    *(float4*)&out[i4] = o;
}

// ---------------------------------------------------------------- launch
extern "C" void kernel_launch(void* const* d_in, const int* in_sizes, int n_in,
                              void* d_out, int out_size, void* d_ws, size_t ws_size,
                              hipStream_t stream) {
    const float* x       = (const float*)d_in[0];   // [32,512,56,56]
    const float* conv_w  = (const float*)d_in[1];   // [64,512]
    const float* conv_b  = (const float*)d_in[2];   // [64]
    const float* centers = (const float*)d_in[3];   // [512,64]
    float* out = (float*)d_out;

    // workspace layout (floats): total ~7.51M floats = 30.0 MB
    float* ws    = (float*)d_ws;
    float* wt    = ws;                          // 32768
    float* alpha = wt + 32768;                  // 6,422,528
    float* asum  = alpha + (size_t)BB*KK*NPIX;  // 2048
    float* vlad  = asum + BB*KK;                // 1,048,576
    float* cninv = vlad + (size_t)BB*DD*KK;     // 2048

    transpose_w   <<<dim3(128),      dim3(256), 0, stream>>>(conv_w, wt);
    logits_softmax<<<dim3(7, BB),    dim3(256), 0, stream>>>(x, wt, conv_b, alpha);
    asum_kernel   <<<dim3(BB * KK),  dim3(64),  0, stream>>>(alpha, asum);
    vlad_gemm     <<<dim3(8, BB),    dim3(256), 0, stream>>>(x, alpha, centers, asum, vlad);
    colnorm_kernel<<<dim3(BB),       dim3(256), 0, stream>>>(vlad, cninv);
    scale_out     <<<dim3(1024),     dim3(256), 0, stream>>>(vlad, cninv, out);
}

// Round 2
// 532.035 us; speedup vs baseline: 1.7199x; 1.7199x over previous
//
#include <hip/hip_runtime.h>
#include <math.h>

// NetVLAD fp32 v2 — occupancy/LDS-tiling restructure.
// B=32, D=512, K=64, N=3136.
// logits: grid(13,32), block tile 64K x 256N, thread tile 8x8, fused softmax via shfl.
// vlad:   grid(2,8,32) n-split partials, block tile 256D x 64K, thread tile 8x8.
// All LDS access patterns <=2-way bank aliasing (free on gfx950 per m136).

#define BB 32
#define DD 512
#define KK 64
#define NPIX 3136
#define NC 48   // vlad inner n-chunk (LDS fits 64 KB static: 48*256*4 + 48*64*4 = 60 KB)

// ---------------------------------------------------------------- kernel 1
__global__ __launch_bounds__(256) void transpose_w(
    const float* __restrict__ w, float* __restrict__ wt)
{
    int i = blockIdx.x * 256 + threadIdx.x;   // < 32768
    int d = i >> 6, k = i & 63;
    wt[i] = w[k * DD + d];
}

// ---------------------------------------------------------------- kernel 2
// grid (13, 32), block 256. Block tile: K=64 x N=256 over full D=512.
// tk = t&7 -> k = tk*8..+7 ; tn = t>>3 -> n = n0 + tn*8..+7. acc[8][8].
// LDS reads per wave per d: 4 b128, each hitting only 8 distinct addrs (broadcast).
__global__ __launch_bounds__(256) void logits_softmax(
    const float* __restrict__ x,      // [B,D,N]
    const float* __restrict__ wt,     // [D,K]
    const float* __restrict__ bias,   // [K]
    float* __restrict__ alpha)        // [B,K,N]
{
    const int b  = blockIdx.y;
    const int n0 = blockIdx.x * 256;
    const int t  = threadIdx.x;
    const int tk = t & 7;
    const int tn = t >> 3;

    __shared__ __align__(16) float xs[32][256];
    __shared__ __align__(16) float ws[32][64];

    float acc[8][8];
    #pragma unroll
    for (int kk = 0; kk < 8; kk++) {
        float bv = bias[tk * 8 + kk];
        #pragma unroll
        for (int j = 0; j < 8; j++) acc[kk][j] = bv;
    }

    const float* xb = x + (size_t)b * DD * NPIX;

    for (int dc = 0; dc < 16; dc++) {
        const int d0 = dc * 32;
        // stage x chunk [32 d][256 n]: 2048 float4
        #pragma unroll
        for (int j = 0; j < 8; j++) {
            int f = j * 256 + t;
            int row = f >> 6, c4 = f & 63;
            int n = n0 + c4 * 4;
            if (n + 3 >= NPIX) n = n0;     // clamp (last tile; values unused)
            *(float4*)&xs[row][c4 * 4] = *(const float4*)&xb[(size_t)(d0 + row) * NPIX + n];
        }
        // stage W chunk [32 d][64 k]: 512 float4
        #pragma unroll
        for (int j = 0; j < 2; j++) {
            int g = j * 256 + t;            // < 512
            int row = g >> 4, c4 = g & 15;
            *(float4*)&ws[row][c4 * 4] = *(const float4*)&wt[(size_t)(d0 + row) * KK + c4 * 4];
        }
        __syncthreads();
        #pragma unroll 4
        for (int dl = 0; dl < 32; dl++) {
            float4 w0 = *(const float4*)&ws[dl][tk * 8];
            float4 w1 = *(const float4*)&ws[dl][tk * 8 + 4];
            float4 x0 = *(const float4*)&xs[dl][tn * 8];
            float4 x1 = *(const float4*)&xs[dl][tn * 8 + 4];
            float wr[8] = {w0.x, w0.y, w0.z, w0.w, w1.x, w1.y, w1.z, w1.w};
            float xr[8] = {x0.x, x0.y, x0.z, x0.w, x1.x, x1.y, x1.z, x1.w};
            #pragma unroll
            for (int kk = 0; kk < 8; kk++)
                #pragma unroll
                for (int j = 0; j < 8; j++)
                    acc[kk][j] = fmaf(wr[kk], xr[j], acc[kk][j]);
        }
        __syncthreads();
    }

    // fused softmax over K=64: the 8 threads covering one pixel group (tk=0..7,
    // same tn) are contiguous lanes -> shfl_xor 1,2,4 reduces across them.
    float rs[8];
    #pragma unroll
    for (int j = 0; j < 8; j++) {
        float m = acc[0][j];
        #pragma unroll
        for (int kk = 1; kk < 8; kk++) m = fmaxf(m, acc[kk][j]);
        m = fmaxf(m, __shfl_xor(m, 1));
        m = fmaxf(m, __shfl_xor(m, 2));
        m = fmaxf(m, __shfl_xor(m, 4));
        float s = 0.f;
        #pragma unroll
        for (int kk = 0; kk < 8; kk++) {
            float e = __expf(acc[kk][j] - m);
            acc[kk][j] = e; s += e;
        }
        s += __shfl_xor(s, 1);
        s += __shfl_xor(s, 2);
        s += __shfl_xor(s, 4);
        rs[j] = 1.0f / s;
    }

    if (n0 + tn * 8 + 7 < NPIX) {
        float* ab = alpha + (size_t)b * KK * NPIX;
        #pragma unroll
        for (int kk = 0; kk < 8; kk++) {
            size_t base = (size_t)(tk * 8 + kk) * NPIX + n0 + tn * 8;
            float4 o0 = make_float4(acc[kk][0] * rs[0], acc[kk][1] * rs[1],
                                    acc[kk][2] * rs[2], acc[kk][3] * rs[3]);
            float4 o1 = make_float4(acc[kk][4] * rs[4], acc[kk][5] * rs[5],
                                    acc[kk][6] * rs[6], acc[kk][7] * rs[7]);
            *(float4*)&ab[base]     = o0;
            *(float4*)&ab[base + 4] = o1;
        }
    }
}

// ---------------------------------------------------------------- kernel 3
__global__ __launch_bounds__(64) void asum_kernel(
    const float* __restrict__ alpha, float* __restrict__ asum)
{
    const int row = blockIdx.x;                  // b*K + k
    const float* p = alpha + (size_t)row * NPIX;
    float s = 0.f;
    for (int n = threadIdx.x; n < NPIX; n += 64) s += p[n];
    #pragma unroll
    for (int off = 32; off; off >>= 1) s += __shfl_down(s, off);
    if (threadIdx.x == 0) asum[row] = s;
}

// ---------------------------------------------------------------- kernel 4
// grid (2, nsplit, 32), block 256. Block tile 256(d) x 64(k), n-chunk NC=48.
// tk = t&7 -> k = tk*8..+7 ; td = t>>3 (0..31) -> d = dtile*256 + td*8..+7.
// LDS n-major: per n-step reads are row-wise, <=2-way bank aliasing everywhere.
__global__ __launch_bounds__(256) void vlad_partial(
    const float* __restrict__ x,        // [B,D,N]
    const float* __restrict__ alpha,    // [B,K,N]
    float* __restrict__ pvlad,          // [nsplit,B,D,K]
    int nchunk)
{
    const int dtile = blockIdx.x;       // 0..1
    const int ns    = blockIdx.y;
    const int b     = blockIdx.z;
    const int t     = threadIdx.x;
    const int tk    = t & 7;
    const int td    = t >> 3;

    __shared__ __align__(16) float xsT[NC][256];
    __shared__ __align__(16) float asT[NC][64];

    float acc[8][8];
    #pragma unroll
    for (int dd = 0; dd < 8; dd++)
        #pragma unroll
        for (int kk = 0; kk < 8; kk++) acc[dd][kk] = 0.f;

    const float* xb = x + ((size_t)b * DD + dtile * 256) * NPIX;
    const float* ab = alpha + (size_t)b * KK * NPIX;

    for (int c = 0; c < nchunk; c += NC) {
        const int nb    = ns * nchunk + c;
        const int valid = min(NC, nchunk - c);   // multiple of 4
        // stage x: thread t owns d-row t; 12 float4 along n, transposed into LDS.
        // store bank = t%32 (2-way, free); read bank = (8*td+c)%32 (conflict-free).
        #pragma unroll
        for (int j = 0; j < 12; j++) {
            float4 v = make_float4(0.f, 0.f, 0.f, 0.f);
            if (j * 4 + 3 < valid)
                v = *(const float4*)&xb[(size_t)t * NPIX + nb + j * 4];
            xsT[j * 4 + 0][t] = v.x;
            xsT[j * 4 + 1][t] = v.y;
            xsT[j * 4 + 2][t] = v.z;
            xsT[j * 4 + 3][t] = v.w;
        }
        // stage alpha: k = t&63, c4 = j*4 + (t>>6): 64 rows x 12 float4.
        #pragma unroll
        for (int j = 0; j < 3; j++) {
            int k  = t & 63;
            int c4 = j * 4 + (t >> 6);
            float4 v = make_float4(0.f, 0.f, 0.f, 0.f);
            if (c4 * 4 + 3 < valid)
                v = *(const float4*)&ab[(size_t)k * NPIX + nb + c4 * 4];
            asT[c4 * 4 + 0][k] = v.x;
            asT[c4 * 4 + 1][k] = v.y;
            asT[c4 * 4 + 2][k] = v.z;
            asT[c4 * 4 + 3][k] = v.w;
        }
        __syncthreads();
        #pragma unroll 4
        for (int n = 0; n < NC; n++) {
            float4 a0 = *(const float4*)&asT[n][tk * 8];
            float4 a1 = *(const float4*)&asT[n][tk * 8 + 4];
            float4 x0 = *(const float4*)&xsT[n][td * 8];
            float4 x1 = *(const float4*)&xsT[n][td * 8 + 4];
            float ar[8] = {a0.x, a0.y, a0.z, a0.w, a1.x, a1.y, a1.z, a1.w};
            float xr[8] = {x0.x, x0.y, x0.z, x0.w, x1.x, x1.y, x1.z, x1.w};
            #pragma unroll
            for (int dd = 0; dd < 8; dd++)
                #pragma unroll
                for (int kk = 0; kk < 8; kk++)
                    acc[dd][kk] = fmaf(xr[dd], ar[kk], acc[dd][kk]);
        }
        __syncthreads();
    }

    float* pv = pvlad + (((size_t)ns * BB + b) * DD + dtile * 256) * KK;
    #pragma unroll
    for (int dd = 0; dd < 8; dd++) {
        int d = td * 8 + dd;
        float4 o0 = make_float4(acc[dd][0], acc[dd][1], acc[dd][2], acc[dd][3]);
        float4 o1 = make_float4(acc[dd][4], acc[dd][5], acc[dd][6], acc[dd][7]);
        *(float4*)&pv[(size_t)d * KK + tk * 8]     = o0;
        *(float4*)&pv[(size_t)d * KK + tk * 8 + 4] = o1;
    }
}

// ---------------------------------------------------------------- kernel 5
// grid (4, 32), block 256: sum partials, subtract centers*asum, write vlad,
// partial column sum-of-squares -> psq[b][dchunk][k].
__global__ __launch_bounds__(256) void combine_norm(
    const float* __restrict__ pvlad, const float* __restrict__ centers,
    const float* __restrict__ asum, float* __restrict__ vlad,
    float* __restrict__ psq, int nsplit)
{
    const int dchunk = blockIdx.x;
    const int b = blockIdx.y;
    const int t = threadIdx.x;
    const int k4 = (t & 15) * 4;
    const int dq = t >> 4;          // 0..15
    const float4 av = *(const float4*)&asum[b * KK + k4];
    float sqx = 0.f, sqy = 0.f, sqz = 0.f, sqw = 0.f;
    for (int i = 0; i < 8; i++) {
        const int d = dchunk * 128 + i * 16 + dq;
        float vx = 0.f, vy = 0.f, vz = 0.f, vw = 0.f;
        for (int ns = 0; ns < nsplit; ns++) {
            const float4 p = *(const float4*)&pvlad[(((size_t)ns * BB + b) * DD + d) * KK + k4];
            vx += p.x; vy += p.y; vz += p.z; vw += p.w;
        }
        const float4 cv = *(const float4*)&centers[d * KK + k4];
        vx -= cv.x * av.x; vy -= cv.y * av.y; vz -= cv.z * av.z; vw -= cv.w * av.w;
        *(float4*)&vlad[((size_t)b * DD + d) * KK + k4] = make_float4(vx, vy, vz, vw);
        sqx = fmaf(vx, vx, sqx); sqy = fmaf(vy, vy, sqy);
        sqz = fmaf(vz, vz, sqz); sqw = fmaf(vw, vw, sqw);
    }
    __shared__ float red[16][64];
    red[dq][k4 + 0] = sqx; red[dq][k4 + 1] = sqy;
    red[dq][k4 + 2] = sqz; red[dq][k4 + 3] = sqw;
    __syncthreads();
    if (t < 64) {
        float s = 0.f;
        #pragma unroll
        for (int q = 0; q < 16; q++) s += red[q][t];
        psq[(b * 4 + dchunk) * 64 + t] = s;
    }
}

// ---------------------------------------------------------------- kernel 6
__global__ __launch_bounds__(64) void colnorm_final(
    const float* __restrict__ psq, float* __restrict__ cninv)
{
    const int b = blockIdx.x, k = threadIdx.x;
    float s = psq[b * 256 + k] + psq[b * 256 + 64 + k]
            + psq[b * 256 + 128 + k] + psq[b * 256 + 192 + k];
    // global norm of K unit columns == sqrt(K) == 8
    cninv[b * 64 + k] = 1.0f / (sqrtf(s) * 8.0f);
}

// ---------------------------------------------------------------- kernel 7
__global__ __launch_bounds__(256) void scale_out(
    const float* __restrict__ vlad, const float* __restrict__ cninv,
    float* __restrict__ out)
{
    const int i4 = (blockIdx.x * 256 + threadIdx.x) * 4;   // < 1048576
    float4 v = *(const float4*)&vlad[i4];
    const int b = i4 >> 15;
    const int k = i4 & 63;
    float4 c = *(const float4*)&cninv[b * KK + k];
    *(float4*)&out[i4] = make_float4(v.x * c.x, v.y * c.y, v.z * c.z, v.w * c.w);
}

// ---------------------------------------------------------------- launch
extern "C" void kernel_launch(void* const* d_in, const int* in_sizes, int n_in,
                              void* d_out, int out_size, void* d_ws, size_t ws_size,
                              hipStream_t stream) {
    const float* x       = (const float*)d_in[0];   // [32,512,56,56]
    const float* conv_w  = (const float*)d_in[1];   // [64,512]
    const float* conv_b  = (const float*)d_in[2];   // [64]
    const float* centers = (const float*)d_in[3];   // [512,64]
    float* out = (float*)d_out;

    // workspace layout (floats)
    float* ws    = (float*)d_ws;
    float* wt    = ws;                 // 32768
    float* alpha = wt + 32768;         // 6,422,528
    float* asum  = alpha + (size_t)BB * KK * NPIX;   // 2048
    float* vlad  = asum + BB * KK;                   // 1,048,576
    float* psq   = vlad + (size_t)BB * DD * KK;      // 8192
    float* cninv = psq + BB * 4 * KK;                // 2048
    float* pvlad = cninv + BB * KK;                  // nsplit * 1,048,576

    const size_t fixed = 32768 + 6422528 + 2048 + 1048576 + 8192 + 2048;
    int nsplit = 8;
    if ((fixed + 8ull * 1048576) * 4 > ws_size) nsplit = 4;
    if ((fixed + 4ull * 1048576) * 4 > ws_size) nsplit = 2;
    const int nchunk = NPIX / nsplit;   // 392 / 784 / 1568, all multiples of 4

    transpose_w   <<<dim3(128),            dim3(256), 0, stream>>>(conv_w, wt);
    logits_softmax<<<dim3(13, BB),         dim3(256), 0, stream>>>(x, wt, conv_b, alpha);
    asum_kernel   <<<dim3(BB * KK),        dim3(64),  0, stream>>>(alpha, asum);
    vlad_partial  <<<dim3(2, nsplit, BB),  dim3(256), 0, stream>>>(x, alpha, pvlad, nchunk);
    combine_norm  <<<dim3(4, BB),          dim3(256), 0, stream>>>(pvlad, centers, asum, vlad, psq, nsplit);
    colnorm_final <<<dim3(BB),             dim3(64),  0, stream>>>(psq, cninv);
    scale_out     <<<dim3(1024),           dim3(256), 0, stream>>>(vlad, cninv, out);
}

// Round 3
// 375.337 us; speedup vs baseline: 2.4380x; 1.4175x over previous
//
#include <hip/hip_runtime.h>
#include <math.h>

// NetVLAD v3 — MFMA (bf16 2-term split) for both GEMMs. B=32, D=512, K=64, N=3136.
// G1: logits+softmax fused, grid(25,32), block tile 64K x 128N, d-chunks of 32.
//     x transposed into LDS as packed u32 (hi|lo bf16), W prepacked by wprep.
//     3 MFMAs per tile-step: Wh*xh + Wh*xl + Wl*xh. Softmax via shfl_xor(16,32).
// G2: vlad partials, grid(4 dtiles, nsplit, 32), block tile 128D x 64K, n-chunks of 32.
//     x natural layout (reduction dim n is contiguous): no transpose. 2 MFMAs: xh*ah + xl*ah.
// alpha stored bf16 (error contribution ~2e-6 at output; threshold 4.5e-4).

#define NN 3136
#define DD 512
#define KK 64
#define BB 32

typedef short bf16x8 __attribute__((ext_vector_type(8)));
typedef float f32x4  __attribute__((ext_vector_type(4)));

#define SEL_HI 0x05040100u   // low 16-bit halves of (hi_src,lo_src) pair -> hi-bf16 frag
#define SEL_LO 0x07060302u   // high 16-bit halves -> lo-bf16 frag

union FragU { uint4 u; bf16x8 f; };

static __device__ inline bf16x8 frag4(unsigned a, unsigned b, unsigned c, unsigned d) {
    FragU x; x.u = make_uint4(a, b, c, d); return x.f;
}

// pack fp32 -> u32 = hi_bf16 | lo_bf16<<16  (truncation split: hi exact bits, lo = trunc(x-hi))
static __device__ inline unsigned pack_split(float f) {
    unsigned u = __float_as_uint(f);
    float hif = __uint_as_float(u & 0xFFFF0000u);
    unsigned lo = __float_as_uint(f - hif) >> 16;
    return (u >> 16) | (lo << 16);
}

static __device__ inline unsigned short bf16_rne(float f) {
    unsigned u = __float_as_uint(f);
    return (unsigned short)((u + 0x7FFFu + ((u >> 16) & 1u)) >> 16);
}

// ---------------------------------------------------------------- wprep
// conv_w is [K=64][D=512] = [cluster][d] — already A-operand major. Pack split.
__global__ __launch_bounds__(256) void wprep_kernel(
    const float* __restrict__ w, unsigned* __restrict__ wp)
{
    int i = blockIdx.x * 256 + threadIdx.x;   // < 32768
    wp[i] = pack_split(w[i]);
}

// ---------------------------------------------------------------- G1
// grid (25, 32), block 256 (4 waves). Block: all 64 clusters x 128 pixels.
// Wave wv owns pixels wv*32..+31 (2 n-tiles). d-chunks of 32 (one MFMA K-step).
__global__ __launch_bounds__(256) void logits_softmax_mfma(
    const float* __restrict__ x,        // [B,D,N] fp32
    const unsigned* __restrict__ wprep, // [64][512] packed
    const float* __restrict__ bias,     // [64]
    unsigned short* __restrict__ alpha) // [B,K,N] bf16
{
    const int b  = blockIdx.y;
    const int n0 = blockIdx.x * 128;
    const int t  = threadIdx.x;
    const int lane = t & 63;
    const int wv   = t >> 6;
    const int c = lane & 15;
    const int q = lane >> 4;

    __shared__ __align__(16) unsigned xs[128][36];  // [n][d] packed, stride 36 dwords
    __shared__ __align__(16) unsigned ws[64][36];   // [cluster][d] packed

    f32x4 acc[4][2];
    #pragma unroll
    for (int mt = 0; mt < 4; mt++)
        #pragma unroll
        for (int r = 0; r < 4; r++) {
            float bv = bias[mt * 16 + q * 4 + r];
            acc[mt][0][r] = bv; acc[mt][1][r] = bv;
        }

    const float* xb = x + (size_t)b * DD * NN;
    const int n4 = t & 31;        // n offset within 32
    const int dr = t >> 5;        // 0..7 -> d col-group

    for (int dc = 0; dc < 16; dc++) {
        // ---- stage x: scalar coalesced reads, packed transpose into LDS.
        // thread covers n = n0 + n4 + 32j (j<4), d = dc*32 + dr*4 + p (p<4).
        #pragma unroll
        for (int j = 0; j < 4; j++) {
            int nn = n0 + n4 + 32 * j;
            if (nn > NN - 1) nn = NN - 1;
            unsigned pk[4];
            #pragma unroll
            for (int p = 0; p < 4; p++) {
                float v = xb[(size_t)(dc * 32 + dr * 4 + p) * NN + nn];
                pk[p] = pack_split(v);
            }
            *(uint4*)&xs[n4 + 32 * j][dr * 4] = make_uint4(pk[0], pk[1], pk[2], pk[3]);
        }
        // ---- stage W: rows t>>2 (64), 4 lanes/row, 2 uint4 each (128 B/row).
        {
            const int row = t >> 2, c4 = t & 3;
            const unsigned* wr = wprep + (size_t)row * DD + dc * 32 + c4 * 8;
            uint4 w0 = *(const uint4*)wr;
            uint4 w1 = *(const uint4*)(wr + 4);
            *(uint4*)&ws[row][c4 * 8]     = w0;
            *(uint4*)&ws[row][c4 * 8 + 4] = w1;
        }
        __syncthreads();

        // ---- fragments
        bf16x8 ah[4], al[4], bh[2], bl[2];
        #pragma unroll
        for (int mt = 0; mt < 4; mt++) {
            uint4 p0 = *(const uint4*)&ws[mt * 16 + c][q * 8];
            uint4 p1 = *(const uint4*)&ws[mt * 16 + c][q * 8 + 4];
            ah[mt] = frag4(__builtin_amdgcn_perm(p0.y, p0.x, SEL_HI),
                           __builtin_amdgcn_perm(p0.w, p0.z, SEL_HI),
                           __builtin_amdgcn_perm(p1.y, p1.x, SEL_HI),
                           __builtin_amdgcn_perm(p1.w, p1.z, SEL_HI));
            al[mt] = frag4(__builtin_amdgcn_perm(p0.y, p0.x, SEL_LO),
                           __builtin_amdgcn_perm(p0.w, p0.z, SEL_LO),
                           __builtin_amdgcn_perm(p1.y, p1.x, SEL_LO),
                           __builtin_amdgcn_perm(p1.w, p1.z, SEL_LO));
        }
        #pragma unroll
        for (int nt = 0; nt < 2; nt++) {
            const int row = wv * 32 + nt * 16 + c;
            uint4 p0 = *(const uint4*)&xs[row][q * 8];
            uint4 p1 = *(const uint4*)&xs[row][q * 8 + 4];
            bh[nt] = frag4(__builtin_amdgcn_perm(p0.y, p0.x, SEL_HI),
                           __builtin_amdgcn_perm(p0.w, p0.z, SEL_HI),
                           __builtin_amdgcn_perm(p1.y, p1.x, SEL_HI),
                           __builtin_amdgcn_perm(p1.w, p1.z, SEL_HI));
            bl[nt] = frag4(__builtin_amdgcn_perm(p0.y, p0.x, SEL_LO),
                           __builtin_amdgcn_perm(p0.w, p0.z, SEL_LO),
                           __builtin_amdgcn_perm(p1.y, p1.x, SEL_LO),
                           __builtin_amdgcn_perm(p1.w, p1.z, SEL_LO));
        }
        #pragma unroll
        for (int mt = 0; mt < 4; mt++)
            #pragma unroll
            for (int nt = 0; nt < 2; nt++) {
                acc[mt][nt] = __builtin_amdgcn_mfma_f32_16x16x32_bf16(ah[mt], bh[nt], acc[mt][nt], 0, 0, 0);
                acc[mt][nt] = __builtin_amdgcn_mfma_f32_16x16x32_bf16(ah[mt], bl[nt], acc[mt][nt], 0, 0, 0);
                acc[mt][nt] = __builtin_amdgcn_mfma_f32_16x16x32_bf16(al[mt], bh[nt], acc[mt][nt], 0, 0, 0);
            }
        __syncthreads();
    }

    // ---- fused softmax over the 64 clusters (in-reg + cross-quad shfl)
    unsigned short* ab = alpha + (size_t)b * KK * NN;
    #pragma unroll
    for (int nt = 0; nt < 2; nt++) {
        float mx = -1e30f;
        #pragma unroll
        for (int mt = 0; mt < 4; mt++)
            #pragma unroll
            for (int r = 0; r < 4; r++) mx = fmaxf(mx, acc[mt][nt][r]);
        mx = fmaxf(mx, __shfl_xor(mx, 16));
        mx = fmaxf(mx, __shfl_xor(mx, 32));
        float s = 0.f;
        #pragma unroll
        for (int mt = 0; mt < 4; mt++)
            #pragma unroll
            for (int r = 0; r < 4; r++) {
                float e = __expf(acc[mt][nt][r] - mx);
                acc[mt][nt][r] = e; s += e;
            }
        s += __shfl_xor(s, 16);
        s += __shfl_xor(s, 32);
        const float rinv = 1.0f / s;
        const int pix = n0 + wv * 32 + nt * 16 + c;
        if (pix < NN) {
            #pragma unroll
            for (int mt = 0; mt < 4; mt++)
                #pragma unroll
                for (int r = 0; r < 4; r++)
                    ab[(size_t)(mt * 16 + q * 4 + r) * NN + pix] = bf16_rne(acc[mt][nt][r] * rinv);
        }
    }
}

// ---------------------------------------------------------------- asum
// grid 2048 (b*K rows), block 64: fp32 row-sum of bf16 alpha.
__global__ __launch_bounds__(64) void asum_kernel(
    const unsigned short* __restrict__ alpha, float* __restrict__ asum)
{
    const int row = blockIdx.x;
    const uint4* p = (const uint4*)(alpha + (size_t)row * NN);  // 392 uint4/row
    float s = 0.f;
    for (int j = threadIdx.x; j < 392; j += 64) {
        uint4 v = p[j];
        unsigned a[4] = {v.x, v.y, v.z, v.w};
        #pragma unroll
        for (int i = 0; i < 4; i++)
            s += __uint_as_float(a[i] << 16) + __uint_as_float(a[i] & 0xFFFF0000u);
    }
    #pragma unroll
    for (int off = 32; off; off >>= 1) s += __shfl_down(s, off);
    if (threadIdx.x == 0) asum[row] = s;
}

// ---------------------------------------------------------------- G2
// grid (4 dtiles, nsplit, 32). Block: 128 d x 64 k, n-chunks of 32.
__global__ __launch_bounds__(256) void vlad_mfma(
    const float* __restrict__ x,              // [B,D,N]
    const unsigned short* __restrict__ alpha, // [B,K,N] bf16
    float* __restrict__ pvlad,                // [nsplit,B,D,K]
    int nchunk)
{
    const int dtile = blockIdx.x;   // 0..3
    const int ns    = blockIdx.y;
    const int b     = blockIdx.z;
    const int t     = threadIdx.x;
    const int lane = t & 63;
    const int wv   = t >> 6;
    const int c = lane & 15;
    const int q = lane >> 4;

    __shared__ __align__(16) unsigned short xh[128][40];  // [d][n] hi, stride 40
    __shared__ __align__(16) unsigned short xl[128][40];
    __shared__ __align__(16) unsigned short as_[64][40];  // [cluster][n] hi

    f32x4 acc[2][4];
    #pragma unroll
    for (int mt = 0; mt < 2; mt++)
        #pragma unroll
        for (int nt = 0; nt < 4; nt++)
            #pragma unroll
            for (int r = 0; r < 4; r++) acc[mt][nt][r] = 0.f;

    const float* xb = x + ((size_t)b * DD + dtile * 128) * NN;
    const int nchunks = nchunk >> 5;

    for (int cc = 0; cc < nchunks; cc++) {
        const int nb = ns * nchunk + cc * 32;
        // ---- stage x: rows t>>3 (+32p), 8 lanes/row (float4 cols).
        {
            const int cg = t & 7, d0 = t >> 3;
            #pragma unroll
            for (int p = 0; p < 4; p++) {
                const int d = d0 + p * 32;
                const int nn = nb + cg * 4;
                float4 v = make_float4(0.f, 0.f, 0.f, 0.f);
                if (nn + 4 <= NN) v = *(const float4*)&xb[(size_t)d * NN + nn];
                unsigned ph[4], pl[4];
                float vv[4] = {v.x, v.y, v.z, v.w};
                #pragma unroll
                for (int i = 0; i < 4; i++) {
                    unsigned pk = pack_split(vv[i]);
                    ph[i] = pk & 0xFFFFu; pl[i] = pk >> 16;
                }
                *(uint2*)&xh[d][cg * 4] = make_uint2(ph[0] | (ph[1] << 16), ph[2] | (ph[3] << 16));
                *(uint2*)&xl[d][cg * 4] = make_uint2(pl[0] | (pl[1] << 16), pl[2] | (pl[3] << 16));
            }
        }
        // ---- stage alpha: rows t>>2 (64), 4 lanes/row, uint4 = 8 bf16.
        {
            const int row = t >> 2, c8 = t & 3;
            uint4 av = make_uint4(0u, 0u, 0u, 0u);
            if (nb + c8 * 8 + 8 <= NN)
                av = *(const uint4*)&alpha[((size_t)b * KK + row) * NN + nb + c8 * 8];
            *(uint4*)&as_[row][c8 * 8] = av;
        }
        __syncthreads();

        bf16x8 ah[2], al2[2], bh[4];
        #pragma unroll
        for (int mt = 0; mt < 2; mt++) {
            const int row = wv * 32 + mt * 16 + c;
            ah[mt]  = *(const bf16x8*)&xh[row][q * 8];
            al2[mt] = *(const bf16x8*)&xl[row][q * 8];
        }
        #pragma unroll
        for (int nt = 0; nt < 4; nt++)
            bh[nt] = *(const bf16x8*)&as_[nt * 16 + c][q * 8];

        #pragma unroll
        for (int mt = 0; mt < 2; mt++)
            #pragma unroll
            for (int nt = 0; nt < 4; nt++) {
                acc[mt][nt] = __builtin_amdgcn_mfma_f32_16x16x32_bf16(ah[mt],  bh[nt], acc[mt][nt], 0, 0, 0);
                acc[mt][nt] = __builtin_amdgcn_mfma_f32_16x16x32_bf16(al2[mt], bh[nt], acc[mt][nt], 0, 0, 0);
            }
        __syncthreads();
    }

    float* pv = pvlad + (((size_t)ns * BB + b) * DD + dtile * 128 + wv * 32) * KK;
    #pragma unroll
    for (int mt = 0; mt < 2; mt++)
        #pragma unroll
        for (int r = 0; r < 4; r++) {
            const int dl = mt * 16 + q * 4 + r;
            #pragma unroll
            for (int nt = 0; nt < 4; nt++)
                pv[(size_t)dl * KK + nt * 16 + c] = acc[mt][nt][r];
        }
}

// ---------------------------------------------------------------- combine
// grid (4, 32), block 256: sum partials, subtract centers*asum, write vlad + psq.
__global__ __launch_bounds__(256) void combine_norm(
    const float* __restrict__ pvlad, const float* __restrict__ centers,
    const float* __restrict__ asum, float* __restrict__ vlad,
    float* __restrict__ psq, int nsplit)
{
    const int dchunk = blockIdx.x;
    const int b = blockIdx.y;
    const int t = threadIdx.x;
    const int k4 = (t & 15) * 4;
    const int dq = t >> 4;          // 0..15
    const float4 av = *(const float4*)&asum[b * KK + k4];
    float sqx = 0.f, sqy = 0.f, sqz = 0.f, sqw = 0.f;
    for (int i = 0; i < 8; i++) {
        const int d = dchunk * 128 + i * 16 + dq;
        float vx = 0.f, vy = 0.f, vz = 0.f, vw = 0.f;
        for (int ns = 0; ns < nsplit; ns++) {
            const float4 p = *(const float4*)&pvlad[(((size_t)ns * BB + b) * DD + d) * KK + k4];
            vx += p.x; vy += p.y; vz += p.z; vw += p.w;
        }
        const float4 cv = *(const float4*)&centers[d * KK + k4];
        vx -= cv.x * av.x; vy -= cv.y * av.y; vz -= cv.z * av.z; vw -= cv.w * av.w;
        *(float4*)&vlad[((size_t)b * DD + d) * KK + k4] = make_float4(vx, vy, vz, vw);
        sqx = fmaf(vx, vx, sqx); sqy = fmaf(vy, vy, sqy);
        sqz = fmaf(vz, vz, sqz); sqw = fmaf(vw, vw, sqw);
    }
    __shared__ float red[16][64];
    red[dq][k4 + 0] = sqx; red[dq][k4 + 1] = sqy;
    red[dq][k4 + 2] = sqz; red[dq][k4 + 3] = sqw;
    __syncthreads();
    if (t < 64) {
        float s = 0.f;
        #pragma unroll
        for (int qq = 0; qq < 16; qq++) s += red[qq][t];
        psq[(b * 4 + dchunk) * 64 + t] = s;
    }
}

__global__ __launch_bounds__(64) void colnorm_final(
    const float* __restrict__ psq, float* __restrict__ cninv)
{
    const int b = blockIdx.x, k = threadIdx.x;
    float s = psq[b * 256 + k] + psq[b * 256 + 64 + k]
            + psq[b * 256 + 128 + k] + psq[b * 256 + 192 + k];
    cninv[b * 64 + k] = 1.0f / (sqrtf(s) * 8.0f);   // global norm of K unit cols == 8
}

__global__ __launch_bounds__(256) void scale_out(
    const float* __restrict__ vlad, const float* __restrict__ cninv,
    float* __restrict__ out)
{
    const int i4 = (blockIdx.x * 256 + threadIdx.x) * 4;   // < 1048576
    float4 v = *(const float4*)&vlad[i4];
    const int b = i4 >> 15;
    const int k = i4 & 63;
    float4 cv = *(const float4*)&cninv[b * KK + k];
    *(float4*)&out[i4] = make_float4(v.x * cv.x, v.y * cv.y, v.z * cv.z, v.w * cv.w);
}

// ---------------------------------------------------------------- launch
extern "C" void kernel_launch(void* const* d_in, const int* in_sizes, int n_in,
                              void* d_out, int out_size, void* d_ws, size_t ws_size,
                              hipStream_t stream) {
    const float* x       = (const float*)d_in[0];
    const float* conv_w  = (const float*)d_in[1];
    const float* conv_b  = (const float*)d_in[2];
    const float* centers = (const float*)d_in[3];
    float* out = (float*)d_out;

    unsigned* wprep       = (unsigned*)d_ws;                         // 32768 u32
    unsigned short* alpha = (unsigned short*)(wprep + 32768);        // 6,422,528 bf16
    float* asum  = (float*)(alpha + (size_t)BB * KK * NN);           // 2048
    float* vlad  = asum + 2048;                                      // 1,048,576
    float* psq   = vlad + 1048576;                                   // 8192
    float* cninv = psq + 8192;                                       // 2048
    float* pvlad = cninv + 2048;                                     // nsplit * 1,048,576

    const size_t fixedB = 131072 + 12845056 + (2048 + 1048576 + 8192 + 2048) * 4ull;
    int nsplit = 7;
    if (fixedB + 7ull * 4194304 > ws_size) nsplit = 4;
    if (fixedB + 4ull * 4194304 > ws_size) nsplit = 2;
    if (fixedB + 2ull * 4194304 > ws_size) nsplit = 1;
    const int nchunk = ((NN + nsplit - 1) / nsplit + 31) & ~31;      // 448 for nsplit=7

    wprep_kernel      <<<dim3(128),             dim3(256), 0, stream>>>(conv_w, wprep);
    logits_softmax_mfma<<<dim3(25, BB),         dim3(256), 0, stream>>>(x, wprep, conv_b, alpha);
    asum_kernel       <<<dim3(BB * KK),         dim3(64),  0, stream>>>(alpha, asum);
    vlad_mfma         <<<dim3(4, nsplit, BB),   dim3(256), 0, stream>>>(x, alpha, pvlad, nchunk);
    combine_norm      <<<dim3(4, BB),           dim3(256), 0, stream>>>(pvlad, centers, asum, vlad, psq, nsplit);
    colnorm_final     <<<dim3(BB),              dim3(64),  0, stream>>>(psq, cninv);
    scale_out         <<<dim3(1024),            dim3(256), 0, stream>>>(vlad, cninv, out);
}